// Round 1
// baseline (7751.489 us; speedup 1.0000x reference)
//
#include <hip/hip_runtime.h>

// ---------------------------------------------------------------------------
// LayerNorm-LSTM (2 layers) + softmax head.  B=1024 T=100 D=300 U=512 C=14
// Round 4:
//   - software-pipeline the two layers across iterations:
//       iter t computes z0(t) AND z1(t-1) in ONE combined GEMM launch
//       (both depend only on h0(t-1), h1(t-2)), then ONE combined LN launch.
//     -> 2 launches/step instead of 4, and 512 resident blocks (2/CU).
//   - gemm_step: K=512 compile-time, explicit 2-deep register double-buffer
//     prefetch; layer-1 interleaves its two K-streams (h0@W1 || h1@U1) for
//     12 independent in-flight loads per phase.
//   - keeps old 4-launch path as fallback for small workspace.
// ---------------------------------------------------------------------------

typedef _Float16 f16;
typedef _Float16 f16x8 __attribute__((ext_vector_type(8)));
typedef float f32x4 __attribute__((ext_vector_type(4)));

// ---------------------------------------------------------------------------
// x [rows,300] fp32 (row stride lda) -> xh [rows,320] f16 zero-padded
// ---------------------------------------------------------------------------
__global__ __launch_bounds__(256) void convert_x(
    const float* __restrict__ x, long lda, f16* __restrict__ xh, int rows) {
  int idx = blockIdx.x * 256 + threadIdx.x;
  if (idx >= rows * 320) return;
  int row = idx / 320, k = idx - row * 320;
  xh[idx] = (k < 300) ? (f16)x[(long)row * lda + k] : (f16)0.f;
}

// ---------------------------------------------------------------------------
// W [K,N] fp32 row-major -> Bt [N,Kp] f16 row-major, zero-padded k in [K,Kp)
// ---------------------------------------------------------------------------
__global__ __launch_bounds__(256) void transpose_f16(
    const float* __restrict__ W, f16* __restrict__ Bt, int K, int N, int Kp) {
  __shared__ float s[32][33];
  int n0 = blockIdx.x * 32, k0 = blockIdx.y * 32;
  int tid = threadIdx.x, c = tid & 31, r8 = tid >> 5;
  for (int rr = r8; rr < 32; rr += 8) {
    int k = k0 + rr;
    s[rr][c] = (k < K) ? W[(long)k * N + (n0 + c)] : 0.0f;
  }
  __syncthreads();
  for (int rr = r8; rr < 32; rr += 8)
    Bt[(long)(n0 + rr) * Kp + (k0 + c)] = (f16)s[c][rr];
}

// ---------------------------------------------------------------------------
// Generic GEMM (direct-global fragments, no LDS) -- used for the big hoisted
// x@W0 GEMM and the fallback path.
//   Z[M, 2048] = (Cin?) + A1[M,K1] @ B1^T + (K2? A2[M,K2] @ B2^T)
// ---------------------------------------------------------------------------
__global__ __launch_bounds__(256) void gemm_f16(
    const f16* __restrict__ A1, long lda1, int K1, const f16* __restrict__ B1,
    const f16* __restrict__ A2, long lda2, int K2, const f16* __restrict__ B2,
    const f16* __restrict__ Cin, long ldc,
    float* __restrict__ Zf, f16* __restrict__ Zh) {
  int tid = threadIdx.x;
  int lane = tid & 63, w = tid >> 6;
  int l15 = lane & 15, quad = lane >> 4;
  long bn0 = (long)blockIdx.x * 128 + w * 32;
  long bm0 = (long)blockIdx.y * 64;

  f32x4 acc[4][2] = {};

  for (int pass = 0; pass < 2; ++pass) {
    int K = pass ? K2 : K1;
    if (K == 0) continue;
    const f16* A = pass ? A2 : A1;
    const f16* Bt = pass ? B2 : B1;
    long lda = pass ? lda2 : lda1;
    const f16* a0 = A + (bm0 + l15) * lda + quad * 8;
    const f16* b0 = Bt + (bn0 + l15) * (long)K + quad * 8;

    for (int k0 = 0; k0 < K; k0 += 32) {
      f16x8 af[4], bf[2];
#pragma unroll
      for (int i = 0; i < 4; ++i)
        af[i] = *(const f16x8*)(a0 + (long)i * 16 * lda + k0);
#pragma unroll
      for (int j = 0; j < 2; ++j)
        bf[j] = *(const f16x8*)(b0 + (long)j * 16 * K + k0);
#pragma unroll
      for (int i = 0; i < 4; ++i)
#pragma unroll
        for (int j = 0; j < 2; ++j)
          acc[i][j] = __builtin_amdgcn_mfma_f32_16x16x32_f16(af[i], bf[j], acc[i][j], 0, 0, 0);
    }
  }

#pragma unroll
  for (int i = 0; i < 4; ++i) {
    long row = bm0 + i * 16 + quad * 4;
#pragma unroll
    for (int j = 0; j < 2; ++j) {
      long col = bn0 + j * 16 + l15;
#pragma unroll
      for (int r = 0; r < 4; ++r) {
        float v = acc[i][j][r];
        if (Cin) v += (float)Cin[(row + r) * ldc + col];
        if (Zf) Zf[(row + r) * 2048 + col] = v;
        else    Zh[(row + r) * 2048 + col] = (f16)v;
      }
    }
  }
}

// ---------------------------------------------------------------------------
// Combined per-step GEMM (pipelined layers):
//   prob 0 (blockIdx.y < 16):  zA = cin0 + h0 @ U0t      (z0 at step t)
//   prob 1 (blockIdx.y >= 16): zB = h0 @ W1t + h1 @ U1t  (z1 at step t-1)
// All A/B have row stride 512 (f16).  K=512 compile-time.
// Block tile 64x128, 4 waves, wave tile 64x32; explicit 2-deep reg prefetch.
// ---------------------------------------------------------------------------
#define LOADF(AF, BF, A0, B0, K0)                          \
  AF[0] = *(const f16x8*)((A0) + (K0));                    \
  AF[1] = *(const f16x8*)((A0) + 16 * 512 + (K0));         \
  AF[2] = *(const f16x8*)((A0) + 32 * 512 + (K0));         \
  AF[3] = *(const f16x8*)((A0) + 48 * 512 + (K0));         \
  BF[0] = *(const f16x8*)((B0) + (K0));                    \
  BF[1] = *(const f16x8*)((B0) + 16 * 512 + (K0));

#define MFMAS(AF, BF)                                                                   \
  acc[0][0] = __builtin_amdgcn_mfma_f32_16x16x32_f16(AF[0], BF[0], acc[0][0], 0, 0, 0); \
  acc[0][1] = __builtin_amdgcn_mfma_f32_16x16x32_f16(AF[0], BF[1], acc[0][1], 0, 0, 0); \
  acc[1][0] = __builtin_amdgcn_mfma_f32_16x16x32_f16(AF[1], BF[0], acc[1][0], 0, 0, 0); \
  acc[1][1] = __builtin_amdgcn_mfma_f32_16x16x32_f16(AF[1], BF[1], acc[1][1], 0, 0, 0); \
  acc[2][0] = __builtin_amdgcn_mfma_f32_16x16x32_f16(AF[2], BF[0], acc[2][0], 0, 0, 0); \
  acc[2][1] = __builtin_amdgcn_mfma_f32_16x16x32_f16(AF[2], BF[1], acc[2][1], 0, 0, 0); \
  acc[3][0] = __builtin_amdgcn_mfma_f32_16x16x32_f16(AF[3], BF[0], acc[3][0], 0, 0, 0); \
  acc[3][1] = __builtin_amdgcn_mfma_f32_16x16x32_f16(AF[3], BF[1], acc[3][1], 0, 0, 0);

__global__ __launch_bounds__(256) void gemm_step(
    const f16* __restrict__ h0, const f16* __restrict__ h1,
    const f16* __restrict__ U0t, const f16* __restrict__ W1t,
    const f16* __restrict__ U1t, const f16* __restrict__ cin0,
    float* __restrict__ zA, float* __restrict__ zB, int do0, int do1) {
  int prob = blockIdx.y >> 4;
  if (prob ? !do1 : !do0) return;
  int tid = threadIdx.x;
  int lane = tid & 63, w = tid >> 6;
  int l15 = lane & 15, quad = lane >> 4;
  long bn0 = (long)blockIdx.x * 128 + w * 32;
  long bm0 = (long)(blockIdx.y & 15) * 64;
  long arow = (bm0 + l15) * 512 + quad * 8;
  long brow = (bn0 + l15) * 512 + quad * 8;

  f32x4 acc[4][2] = {};

  if (prob == 0) {
    const f16* a0 = h0 + arow;
    const f16* b0 = U0t + brow;
    f16x8 af0[4], bf0[2], af1[4], bf1[2];
    LOADF(af0, bf0, a0, b0, 0)
    for (int k0 = 0; k0 < 448; k0 += 64) {
      LOADF(af1, bf1, a0, b0, k0 + 32)
      MFMAS(af0, bf0)
      LOADF(af0, bf0, a0, b0, k0 + 64)
      MFMAS(af1, bf1)
    }
    {
      LOADF(af1, bf1, a0, b0, 480)
      MFMAS(af0, bf0)  // k=448
      MFMAS(af1, bf1)  // k=480
    }
  } else {
    // interleave the two K-streams: 12 independent loads in flight per phase
    const f16* ax = h0 + arow;
    const f16* bx = W1t + brow;
    const f16* ay = h1 + arow;
    const f16* by = U1t + brow;
    f16x8 axf0[4], bxf0[2], axf1[4], bxf1[2];
    f16x8 ayf0[4], byf0[2], ayf1[4], byf1[2];
    LOADF(axf0, bxf0, ax, bx, 0)
    LOADF(ayf0, byf0, ay, by, 0)
    for (int k0 = 0; k0 < 448; k0 += 64) {
      LOADF(axf1, bxf1, ax, bx, k0 + 32)
      LOADF(ayf1, byf1, ay, by, k0 + 32)
      MFMAS(axf0, bxf0)
      MFMAS(ayf0, byf0)
      LOADF(axf0, bxf0, ax, bx, k0 + 64)
      LOADF(ayf0, byf0, ay, by, k0 + 64)
      MFMAS(axf1, bxf1)
      MFMAS(ayf1, byf1)
    }
    {
      LOADF(axf1, bxf1, ax, bx, 480)
      LOADF(ayf1, byf1, ay, by, 480)
      MFMAS(axf0, bxf0)
      MFMAS(ayf0, byf0)
      MFMAS(axf1, bxf1)
      MFMAS(ayf1, byf1)
    }
  }

  float* Z = prob ? zB : zA;
#pragma unroll
  for (int i = 0; i < 4; ++i) {
    long row = bm0 + i * 16 + quad * 4;
#pragma unroll
    for (int j = 0; j < 2; ++j) {
      long col = bn0 + j * 16 + l15;
#pragma unroll
      for (int r = 0; r < 4; ++r) {
        float v = acc[i][j][r];
        if (prob == 0) v += (float)cin0[(row + r) * 204800L + col];
        Z[(row + r) * 2048 + col] = v;
      }
    }
  }
}

// ---------------------------------------------------------------------------
// LayerNorm + gates + cell/hidden update + mask -- single layer (fallback).
// ---------------------------------------------------------------------------
__global__ __launch_bounds__(256) void ln_gates(
    const float* __restrict__ z, const float* __restrict__ gamma,
    const float* __restrict__ beta, const float* __restrict__ bias,
    const int* __restrict__ mask, int t,
    f16* __restrict__ h, float* __restrict__ c) {
  __shared__ float act[2048];
  int b = blockIdx.x;
  int tid = threadIdx.x;
  int w = tid >> 6, lane = tid & 63;

  const float* zb = z + (long)b * 2048 + w * 512;
  float zv[8];
  float sum = 0.0f, sq = 0.0f;
#pragma unroll
  for (int i = 0; i < 8; ++i) {
    float v = zb[lane + 64 * i];
    zv[i] = v;
    sum += v;
    sq += v * v;
  }
#pragma unroll
  for (int off = 32; off; off >>= 1) {
    sum += __shfl_xor(sum, off);
    sq += __shfl_xor(sq, off);
  }
  float mu = sum * (1.0f / 512.0f);
  float var = sq * (1.0f / 512.0f) - mu * mu;
  float is = rsqrtf(var + 1e-3f);

#pragma unroll
  for (int i = 0; i < 8; ++i) {
    int k = lane + 64 * i;
    float val = gamma[w * 512 + k] * (zv[i] - mu) * is + beta[w * 512 + k] + bias[w * 512 + k];
    float a;
    if (w == 2) {
      a = 2.0f / (1.0f + __expf(-2.0f * val)) - 1.0f;
    } else {
      a = 1.0f / (1.0f + __expf(-val));
    }
    act[w * 512 + k] = a;
  }
  __syncthreads();

  bool m = mask[(long)b * 100 + t] > 0;
#pragma unroll
  for (int i = 0; i < 2; ++i) {
    int u = tid + 256 * i;
    float co = c[(long)b * 512 + u];
    float ho = (float)h[(long)b * 512 + u];
    float cn = act[512 + u] * co + act[u] * act[1024 + u];
    float th = 2.0f / (1.0f + __expf(-2.0f * cn)) - 1.0f;
    float hn = act[1536 + u] * th;
    h[(long)b * 512 + u] = (f16)(m ? hn : ho);
    c[(long)b * 512 + u] = m ? cn : co;
  }
}

// ---------------------------------------------------------------------------
// Combined LN for the pipelined path:
//   blocks [0,1024)    : layer 0, z=zA, mask time t     (if do0)
//   blocks [1024,2048) : layer 1, z=zB, mask time t-1   (if do1)
// ---------------------------------------------------------------------------
__global__ __launch_bounds__(256) void ln_gates2(
    const float* __restrict__ zA, const float* __restrict__ zB,
    const float* __restrict__ g0, const float* __restrict__ be0,
    const float* __restrict__ b0, const float* __restrict__ g1,
    const float* __restrict__ be1, const float* __restrict__ b1,
    const int* __restrict__ mask, int t,
    f16* __restrict__ h0, float* __restrict__ c0,
    f16* __restrict__ h1, float* __restrict__ c1, int do0, int do1) {
  __shared__ float act[2048];
  int layer = blockIdx.x >> 10;
  if (layer ? !do1 : !do0) return;
  int b = blockIdx.x & 1023;
  const float* z = layer ? zB : zA;
  const float* gamma = layer ? g1 : g0;
  const float* beta = layer ? be1 : be0;
  const float* bias = layer ? b1 : b0;
  f16* h = layer ? h1 : h0;
  float* c = layer ? c1 : c0;
  int tm = layer ? (t - 1) : t;

  int tid = threadIdx.x;
  int w = tid >> 6, lane = tid & 63;

  const float* zb = z + (long)b * 2048 + w * 512;
  float zv[8];
  float sum = 0.0f, sq = 0.0f;
#pragma unroll
  for (int i = 0; i < 8; ++i) {
    float v = zb[lane + 64 * i];
    zv[i] = v;
    sum += v;
    sq += v * v;
  }
#pragma unroll
  for (int off = 32; off; off >>= 1) {
    sum += __shfl_xor(sum, off);
    sq += __shfl_xor(sq, off);
  }
  float mu = sum * (1.0f / 512.0f);
  float var = sq * (1.0f / 512.0f) - mu * mu;
  float is = rsqrtf(var + 1e-3f);

#pragma unroll
  for (int i = 0; i < 8; ++i) {
    int k = lane + 64 * i;
    float val = gamma[w * 512 + k] * (zv[i] - mu) * is + beta[w * 512 + k] + bias[w * 512 + k];
    float a;
    if (w == 2) {
      a = 2.0f / (1.0f + __expf(-2.0f * val)) - 1.0f;
    } else {
      a = 1.0f / (1.0f + __expf(-val));
    }
    act[w * 512 + k] = a;
  }
  __syncthreads();

  bool m = mask[(long)b * 100 + tm] > 0;
#pragma unroll
  for (int i = 0; i < 2; ++i) {
    int u = tid + 256 * i;
    float co = c[(long)b * 512 + u];
    float ho = (float)h[(long)b * 512 + u];
    float cn = act[512 + u] * co + act[u] * act[1024 + u];
    float th = 2.0f / (1.0f + __expf(-2.0f * cn)) - 1.0f;
    float hn = act[1536 + u] * th;
    h[(long)b * 512 + u] = (f16)(m ? hn : ho);
    c[(long)b * 512 + u] = m ? cn : co;
  }
}

// ---------------------------------------------------------------------------
// Head: out[b,:] = softmax(h1[b,:] @ Wd + bd)
// ---------------------------------------------------------------------------
__global__ __launch_bounds__(64) void head_kernel(
    const f16* __restrict__ h, const float* __restrict__ Wd,
    const float* __restrict__ bd, float* __restrict__ out) {
  __shared__ float hs[512];
  __shared__ float lg[16];
  int b = blockIdx.x, tid = threadIdx.x;
#pragma unroll
  for (int i = 0; i < 8; ++i) hs[tid + 64 * i] = (float)h[(long)b * 512 + tid + 64 * i];
  __syncthreads();
  if (tid < 14) {
    float s = bd[tid];
    for (int k = 0; k < 512; ++k) s += hs[k] * Wd[k * 14 + tid];
    lg[tid] = s;
  }
  __syncthreads();
  if (tid < 14) {
    float mx = lg[0];
#pragma unroll
    for (int i = 1; i < 14; ++i) mx = fmaxf(mx, lg[i]);
    float e = __expf(lg[tid] - mx);
    float den = 0.0f;
#pragma unroll
    for (int i = 0; i < 14; ++i) den += __expf(lg[i] - mx);
    out[(long)b * 14 + tid] = e / den;
  }
}

// ---------------------------------------------------------------------------
extern "C" void kernel_launch(void* const* d_in, const int* in_sizes, int n_in,
                              void* d_out, int out_size, void* d_ws, size_t ws_size,
                              hipStream_t stream) {
  const float* x   = (const float*)d_in[0];
  const int* mask  = (const int*)d_in[1];
  const float* W0  = (const float*)d_in[2];
  const float* U0w = (const float*)d_in[3];
  const float* b0  = (const float*)d_in[4];
  const float* g0  = (const float*)d_in[5];
  const float* be0 = (const float*)d_in[6];
  const float* W1  = (const float*)d_in[7];
  const float* U1w = (const float*)d_in[8];
  const float* b1  = (const float*)d_in[9];
  const float* g1  = (const float*)d_in[10];
  const float* be1 = (const float*)d_in[11];
  const float* Wd  = (const float*)d_in[12];
  const float* bd  = (const float*)d_in[13];
  float* out = (float*)d_out;

  char* p = (char*)d_ws;
  f16*   h0  = (f16*)(p + 0);                       // 1 MB
  f16*   h1  = (f16*)(p + ((size_t)1 << 20));       // 1 MB
  float* c0  = (float*)(p + ((size_t)2 << 20));     // 2 MB
  float* c1  = (float*)(p + ((size_t)4 << 20));     // 2 MB
  float* z   = (float*)(p + ((size_t)6 << 20));     // 8 MB  [6,14)   (zA)
  f16*   W0t = (f16*)(p + ((size_t)14 << 20));
  f16*   U0t = (f16*)(p + ((size_t)14 << 20) + 1310720);
  f16*   W1t = (f16*)(p + ((size_t)14 << 20) + 1310720 + 2097152);
  f16*   U1t = (f16*)(p + ((size_t)14 << 20) + 1310720 + 2 * 2097152);
  f16*   xh  = (f16*)(p + ((size_t)22 << 20));      // used only BEFORE the loop in hoist mode
  float* zB  = (float*)(p + ((size_t)22 << 20));    // 8 MB, reuses xh region (dead after hoist GEMM)
  f16*   z0x = (f16*)(p + ((size_t)96 << 20));      // 102400*2048*2

  const size_t need_hoist = ((size_t)96 << 20) + (size_t)102400 * 2048 * 2;
  const size_t need_xh    = ((size_t)22 << 20) + (size_t)102400 * 320 * 2;
  const bool hoist   = ws_size >= need_hoist;
  const bool full_xh = ws_size >= need_xh;

  hipMemsetAsync(p, 0, (size_t)6 << 20, stream);

  transpose_f16<<<dim3(64, 10), 256, 0, stream>>>(W0,  W0t, 300, 2048, 320);
  transpose_f16<<<dim3(64, 16), 256, 0, stream>>>(U0w, U0t, 512, 2048, 512);
  transpose_f16<<<dim3(64, 16), 256, 0, stream>>>(W1,  W1t, 512, 2048, 512);
  transpose_f16<<<dim3(64, 16), 256, 0, stream>>>(U1w, U1t, 512, 2048, 512);

  if (full_xh) {
    convert_x<<<(102400 * 320 + 255) / 256, 256, 0, stream>>>(x, 300, xh, 102400);
  }

  if (hoist) {
    // z0x[b*100+t, :] = x[b,t,:] @ W0   (one big parallel GEMM, f16 out)
    gemm_f16<<<dim3(16, 1600), 256, 0, stream>>>(
        xh, 320, 320, W0t, nullptr, 0, 0, nullptr, nullptr, 0, nullptr, z0x);

    // pipelined layers: iteration t computes z0(t) and z1(t-1) together.
    for (int t = 0; t <= 100; ++t) {
      int do0 = (t < 100) ? 1 : 0;
      int do1 = (t >= 1) ? 1 : 0;
      gemm_step<<<dim3(16, 32), 256, 0, stream>>>(
          h0, h1, U0t, W1t, U1t, z0x + (long)t * 2048, z, zB, do0, do1);
      ln_gates2<<<2048, 256, 0, stream>>>(
          z, zB, g0, be0, b0, g1, be1, b1, mask, t, h0, c0, h1, c1, do0, do1);
    }
  } else {
    // fallback: original 4-launch-per-step structure
    for (int t = 0; t < 100; ++t) {
      if (full_xh) {
        gemm_f16<<<dim3(16, 16), 256, 0, stream>>>(
            xh + (long)t * 320, 32000, 320, W0t, h0, 512, 512, U0t,
            nullptr, 0, z, nullptr);
      } else {
        convert_x<<<(1024 * 320 + 255) / 256, 256, 0, stream>>>(x + (long)t * 300, 30000, xh, 1024);
        gemm_f16<<<dim3(16, 16), 256, 0, stream>>>(
            xh, 320, 320, W0t, h0, 512, 512, U0t, nullptr, 0, z, nullptr);
      }
      ln_gates<<<1024, 256, 0, stream>>>(z, g0, be0, b0, mask, t, h0, c0);
      gemm_f16<<<dim3(16, 16), 256, 0, stream>>>(
          h0, 512, 512, W1t, h1, 512, 512, U1t, nullptr, 0, z, nullptr);
      ln_gates<<<1024, 256, 0, stream>>>(z, g1, be1, b1, mask, t, h1, c1);
    }
  }

  head_kernel<<<1024, 64, 0, stream>>>(h1, Wd, bd, out);
}

// Round 2
// 5768.138 us; speedup vs baseline: 1.3438x; 1.3438x over previous
//
#include <hip/hip_runtime.h>

// ---------------------------------------------------------------------------
// LayerNorm-LSTM (2 layers) + softmax head.  B=1024 T=100 D=300 U=512 C=14
// Round 5:
//   - Round-4 pipelined path never ran: its guard needed ws >= 520 MB
//     (identical timing r0 vs r1 proves the fallback executed both times).
//   - This round: pipelined path fits in 30 MiB. x@W0 is computed inside
//     gemm_step prob-0 by loading fp32 x directly with in-register f16
//     conversion (K=300: 9 vector k-steps + guarded tail). No hoist buffer,
//     no full-T xh.
//   - Pipeline skew: iter t computes z0(t) AND z1(t-1) in one GEMM launch,
//     then one combined LN launch.  2 launches/step, 512 blocks/GEMM.
// ---------------------------------------------------------------------------

typedef _Float16 f16;
typedef _Float16 f16x8 __attribute__((ext_vector_type(8)));
typedef float f32x4 __attribute__((ext_vector_type(4)));

// ---------------------------------------------------------------------------
// x [rows,300] fp32 (row stride lda) -> xh [rows,320] f16 zero-padded
// (fallback path only)
// ---------------------------------------------------------------------------
__global__ __launch_bounds__(256) void convert_x(
    const float* __restrict__ x, long lda, f16* __restrict__ xh, int rows) {
  int idx = blockIdx.x * 256 + threadIdx.x;
  if (idx >= rows * 320) return;
  int row = idx / 320, k = idx - row * 320;
  xh[idx] = (k < 300) ? (f16)x[(long)row * lda + k] : (f16)0.f;
}

// ---------------------------------------------------------------------------
// W [K,N] fp32 row-major -> Bt [N,Kp] f16 row-major, zero-padded k in [K,Kp)
// ---------------------------------------------------------------------------
__global__ __launch_bounds__(256) void transpose_f16(
    const float* __restrict__ W, f16* __restrict__ Bt, int K, int N, int Kp) {
  __shared__ float s[32][33];
  int n0 = blockIdx.x * 32, k0 = blockIdx.y * 32;
  int tid = threadIdx.x, c = tid & 31, r8 = tid >> 5;
  for (int rr = r8; rr < 32; rr += 8) {
    int k = k0 + rr;
    s[rr][c] = (k < K) ? W[(long)k * N + (n0 + c)] : 0.0f;
  }
  __syncthreads();
  for (int rr = r8; rr < 32; rr += 8)
    Bt[(long)(n0 + rr) * Kp + (k0 + c)] = (f16)s[c][rr];
}

// ---------------------------------------------------------------------------
// Generic GEMM (fallback path):
//   Z[M, 2048] = A1[M,K1] @ B1^T + (K2? A2[M,K2] @ B2^T)
// ---------------------------------------------------------------------------
__global__ __launch_bounds__(256) void gemm_f16(
    const f16* __restrict__ A1, long lda1, int K1, const f16* __restrict__ B1,
    const f16* __restrict__ A2, long lda2, int K2, const f16* __restrict__ B2,
    float* __restrict__ Zf) {
  int tid = threadIdx.x;
  int lane = tid & 63, w = tid >> 6;
  int l15 = lane & 15, quad = lane >> 4;
  long bn0 = (long)blockIdx.x * 128 + w * 32;
  long bm0 = (long)blockIdx.y * 64;

  f32x4 acc[4][2] = {};

  for (int pass = 0; pass < 2; ++pass) {
    int K = pass ? K2 : K1;
    if (K == 0) continue;
    const f16* A = pass ? A2 : A1;
    const f16* Bt = pass ? B2 : B1;
    long lda = pass ? lda2 : lda1;
    const f16* a0 = A + (bm0 + l15) * lda + quad * 8;
    const f16* b0 = Bt + (bn0 + l15) * (long)K + quad * 8;

    for (int k0 = 0; k0 < K; k0 += 32) {
      f16x8 af[4], bf[2];
#pragma unroll
      for (int i = 0; i < 4; ++i)
        af[i] = *(const f16x8*)(a0 + (long)i * 16 * lda + k0);
#pragma unroll
      for (int j = 0; j < 2; ++j)
        bf[j] = *(const f16x8*)(b0 + (long)j * 16 * K + k0);
#pragma unroll
      for (int i = 0; i < 4; ++i)
#pragma unroll
        for (int j = 0; j < 2; ++j)
          acc[i][j] = __builtin_amdgcn_mfma_f32_16x16x32_f16(af[i], bf[j], acc[i][j], 0, 0, 0);
    }
  }

#pragma unroll
  for (int i = 0; i < 4; ++i) {
    long row = bm0 + i * 16 + quad * 4;
#pragma unroll
    for (int j = 0; j < 2; ++j) {
      long col = bn0 + j * 16 + l15;
#pragma unroll
      for (int r = 0; r < 4; ++r)
        Zf[(row + r) * 2048 + col] = acc[i][j][r];
    }
  }
}

// ---------------------------------------------------------------------------
// Combined per-step GEMM (pipelined layers):
//   prob 0 (blockIdx.y < 16):  zA = x_t @ W0 + h0 @ U0      (z0 at step t)
//   prob 1 (blockIdx.y >= 16): zB = h0 @ W1 + h1 @ U1       (z1 at step t-1)
// x loaded fp32 directly (row stride 30000), converted in-register.
// Block tile 64x128: 4 waves, wave tile 64x32; 2-deep register prefetch.
// ---------------------------------------------------------------------------
#define LOADF(AF, BF, A0, B0, K0)                          \
  AF[0] = *(const f16x8*)((A0) + (K0));                    \
  AF[1] = *(const f16x8*)((A0) + 16 * 512 + (K0));         \
  AF[2] = *(const f16x8*)((A0) + 32 * 512 + (K0));         \
  AF[3] = *(const f16x8*)((A0) + 48 * 512 + (K0));         \
  BF[0] = *(const f16x8*)((B0) + (K0));                    \
  BF[1] = *(const f16x8*)((B0) + 16 * 512 + (K0));

#define MFMAS(AF, BF)                                                                   \
  acc[0][0] = __builtin_amdgcn_mfma_f32_16x16x32_f16(AF[0], BF[0], acc[0][0], 0, 0, 0); \
  acc[0][1] = __builtin_amdgcn_mfma_f32_16x16x32_f16(AF[0], BF[1], acc[0][1], 0, 0, 0); \
  acc[1][0] = __builtin_amdgcn_mfma_f32_16x16x32_f16(AF[1], BF[0], acc[1][0], 0, 0, 0); \
  acc[1][1] = __builtin_amdgcn_mfma_f32_16x16x32_f16(AF[1], BF[1], acc[1][1], 0, 0, 0); \
  acc[2][0] = __builtin_amdgcn_mfma_f32_16x16x32_f16(AF[2], BF[0], acc[2][0], 0, 0, 0); \
  acc[2][1] = __builtin_amdgcn_mfma_f32_16x16x32_f16(AF[2], BF[1], acc[2][1], 0, 0, 0); \
  acc[3][0] = __builtin_amdgcn_mfma_f32_16x16x32_f16(AF[3], BF[0], acc[3][0], 0, 0, 0); \
  acc[3][1] = __builtin_amdgcn_mfma_f32_16x16x32_f16(AF[3], BF[1], acc[3][1], 0, 0, 0);

__global__ __launch_bounds__(256, 2) void gemm_step(
    const float* __restrict__ xt,   // x + t*300, row stride 30000 fp32
    const f16* __restrict__ h0, const f16* __restrict__ h1,
    const f16* __restrict__ W0t,    // [2048][320] f16, zero-padded k>=300
    const f16* __restrict__ U0t, const f16* __restrict__ W1t,
    const f16* __restrict__ U1t,
    float* __restrict__ zA, float* __restrict__ zB, int do0, int do1) {
  int prob = blockIdx.y >> 4;
  if (prob ? !do1 : !do0) return;
  int tid = threadIdx.x;
  int lane = tid & 63, w = tid >> 6;
  int l15 = lane & 15, quad = lane >> 4;
  long bn0 = (long)blockIdx.x * 128 + w * 32;
  long bm0 = (long)(blockIdx.y & 15) * 64;
  long arow = (bm0 + l15) * 512 + quad * 8;
  long brow = (bn0 + l15) * 512 + quad * 8;

  f32x4 acc[4][2] = {};

  if (prob == 0) {
    // ---- pass 1: x_t @ W0, K=300 (9 vector k-steps + guarded tail) ----
    {
      const float* ax = xt + (bm0 + l15) * 30000L + quad * 8;
      const f16* bw = W0t + (bn0 + l15) * 320L + quad * 8;
#pragma unroll
      for (int k0 = 0; k0 < 288; k0 += 32) {
        f16x8 af[4], bf[2];
#pragma unroll
        for (int i = 0; i < 4; ++i) {
          f32x4 lo = *(const f32x4*)(ax + (long)i * 480000 + k0);
          f32x4 hi = *(const f32x4*)(ax + (long)i * 480000 + k0 + 4);
#pragma unroll
          for (int e = 0; e < 4; ++e) {
            af[i][e] = (f16)lo[e];
            af[i][4 + e] = (f16)hi[e];
          }
        }
        bf[0] = *(const f16x8*)(bw + k0);
        bf[1] = *(const f16x8*)(bw + 16 * 320 + k0);
        MFMAS(af, bf)
      }
      {  // tail k0=288: k in [288,320), valid only k<300 (W0t zero beyond)
        f16x8 af[4], bf[2];
#pragma unroll
        for (int i = 0; i < 4; ++i) {
          long rb = (bm0 + l15 + i * 16) * 30000L;
#pragma unroll
          for (int e = 0; e < 8; ++e) {
            int k = 288 + quad * 8 + e;
            af[i][e] = (k < 300) ? (f16)xt[rb + k] : (f16)0.f;
          }
        }
        bf[0] = *(const f16x8*)(bw + 288);
        bf[1] = *(const f16x8*)(bw + 16 * 320 + 288);
        MFMAS(af, bf)
      }
    }
    // ---- pass 2: h0 @ U0, K=512, 2-deep register prefetch ----
    {
      const f16* a0 = h0 + arow;
      const f16* b0 = U0t + brow;
      f16x8 af0[4], bf0[2], af1[4], bf1[2];
      LOADF(af0, bf0, a0, b0, 0)
      for (int k0 = 0; k0 < 448; k0 += 64) {
        LOADF(af1, bf1, a0, b0, k0 + 32)
        MFMAS(af0, bf0)
        LOADF(af0, bf0, a0, b0, k0 + 64)
        MFMAS(af1, bf1)
      }
      LOADF(af1, bf1, a0, b0, 480)
      MFMAS(af0, bf0)
      MFMAS(af1, bf1)
    }
  } else {
    // ---- z1(t-1): interleave two K-streams (h0@W1 || h1@U1) ----
    const f16* ax = h0 + arow;
    const f16* bx = W1t + brow;
    const f16* ay = h1 + arow;
    const f16* by = U1t + brow;
    f16x8 axf0[4], bxf0[2], axf1[4], bxf1[2];
    f16x8 ayf0[4], byf0[2], ayf1[4], byf1[2];
    LOADF(axf0, bxf0, ax, bx, 0)
    LOADF(ayf0, byf0, ay, by, 0)
    for (int k0 = 0; k0 < 448; k0 += 64) {
      LOADF(axf1, bxf1, ax, bx, k0 + 32)
      LOADF(ayf1, byf1, ay, by, k0 + 32)
      MFMAS(axf0, bxf0)
      MFMAS(ayf0, byf0)
      LOADF(axf0, bxf0, ax, bx, k0 + 64)
      LOADF(ayf0, byf0, ay, by, k0 + 64)
      MFMAS(axf1, bxf1)
      MFMAS(ayf1, byf1)
    }
    LOADF(axf1, bxf1, ax, bx, 480)
    LOADF(ayf1, byf1, ay, by, 480)
    MFMAS(axf0, bxf0)
    MFMAS(ayf0, byf0)
    MFMAS(axf1, bxf1)
    MFMAS(ayf1, byf1)
  }

  float* Z = prob ? zB : zA;
#pragma unroll
  for (int i = 0; i < 4; ++i) {
    long row = bm0 + i * 16 + quad * 4;
#pragma unroll
    for (int j = 0; j < 2; ++j) {
      long col = bn0 + j * 16 + l15;
#pragma unroll
      for (int r = 0; r < 4; ++r)
        Z[(row + r) * 2048 + col] = acc[i][j][r];
    }
  }
}

// ---------------------------------------------------------------------------
// LayerNorm + gates + cell/hidden update + mask -- single layer (fallback).
// ---------------------------------------------------------------------------
__global__ __launch_bounds__(256) void ln_gates(
    const float* __restrict__ z, const float* __restrict__ gamma,
    const float* __restrict__ beta, const float* __restrict__ bias,
    const int* __restrict__ mask, int t,
    f16* __restrict__ h, float* __restrict__ c) {
  __shared__ float act[2048];
  int b = blockIdx.x;
  int tid = threadIdx.x;
  int w = tid >> 6, lane = tid & 63;

  const float* zb = z + (long)b * 2048 + w * 512;
  float zv[8];
  float sum = 0.0f, sq = 0.0f;
#pragma unroll
  for (int i = 0; i < 8; ++i) {
    float v = zb[lane + 64 * i];
    zv[i] = v;
    sum += v;
    sq += v * v;
  }
#pragma unroll
  for (int off = 32; off; off >>= 1) {
    sum += __shfl_xor(sum, off);
    sq += __shfl_xor(sq, off);
  }
  float mu = sum * (1.0f / 512.0f);
  float var = sq * (1.0f / 512.0f) - mu * mu;
  float is = rsqrtf(var + 1e-3f);

#pragma unroll
  for (int i = 0; i < 8; ++i) {
    int k = lane + 64 * i;
    float val = gamma[w * 512 + k] * (zv[i] - mu) * is + beta[w * 512 + k] + bias[w * 512 + k];
    float a;
    if (w == 2) {
      a = 2.0f / (1.0f + __expf(-2.0f * val)) - 1.0f;
    } else {
      a = 1.0f / (1.0f + __expf(-val));
    }
    act[w * 512 + k] = a;
  }
  __syncthreads();

  bool m = mask[(long)b * 100 + t] > 0;
#pragma unroll
  for (int i = 0; i < 2; ++i) {
    int u = tid + 256 * i;
    float co = c[(long)b * 512 + u];
    float ho = (float)h[(long)b * 512 + u];
    float cn = act[512 + u] * co + act[u] * act[1024 + u];
    float th = 2.0f / (1.0f + __expf(-2.0f * cn)) - 1.0f;
    float hn = act[1536 + u] * th;
    h[(long)b * 512 + u] = (f16)(m ? hn : ho);
    c[(long)b * 512 + u] = m ? cn : co;
  }
}

// ---------------------------------------------------------------------------
// Combined LN for the pipelined path:
//   blocks [0,1024)    : layer 0, z=zA, mask time t     (if do0)
//   blocks [1024,2048) : layer 1, z=zB, mask time t-1   (if do1)
// ---------------------------------------------------------------------------
__global__ __launch_bounds__(256) void ln_gates2(
    const float* __restrict__ zA, const float* __restrict__ zB,
    const float* __restrict__ g0, const float* __restrict__ be0,
    const float* __restrict__ b0, const float* __restrict__ g1,
    const float* __restrict__ be1, const float* __restrict__ b1,
    const int* __restrict__ mask, int t,
    f16* __restrict__ h0, float* __restrict__ c0,
    f16* __restrict__ h1, float* __restrict__ c1, int do0, int do1) {
  __shared__ float act[2048];
  int layer = blockIdx.x >> 10;
  if (layer ? !do1 : !do0) return;
  int b = blockIdx.x & 1023;
  const float* z = layer ? zB : zA;
  const float* gamma = layer ? g1 : g0;
  const float* beta = layer ? be1 : be0;
  const float* bias = layer ? b1 : b0;
  f16* h = layer ? h1 : h0;
  float* c = layer ? c1 : c0;
  int tm = layer ? (t - 1) : t;

  int tid = threadIdx.x;
  int w = tid >> 6, lane = tid & 63;

  const float* zb = z + (long)b * 2048 + w * 512;
  float zv[8];
  float sum = 0.0f, sq = 0.0f;
#pragma unroll
  for (int i = 0; i < 8; ++i) {
    float v = zb[lane + 64 * i];
    zv[i] = v;
    sum += v;
    sq += v * v;
  }
#pragma unroll
  for (int off = 32; off; off >>= 1) {
    sum += __shfl_xor(sum, off);
    sq += __shfl_xor(sq, off);
  }
  float mu = sum * (1.0f / 512.0f);
  float var = sq * (1.0f / 512.0f) - mu * mu;
  float is = rsqrtf(var + 1e-3f);

#pragma unroll
  for (int i = 0; i < 8; ++i) {
    int k = lane + 64 * i;
    float val = gamma[w * 512 + k] * (zv[i] - mu) * is + beta[w * 512 + k] + bias[w * 512 + k];
    float a;
    if (w == 2) {
      a = 2.0f / (1.0f + __expf(-2.0f * val)) - 1.0f;
    } else {
      a = 1.0f / (1.0f + __expf(-val));
    }
    act[w * 512 + k] = a;
  }
  __syncthreads();

  bool m = mask[(long)b * 100 + tm] > 0;
#pragma unroll
  for (int i = 0; i < 2; ++i) {
    int u = tid + 256 * i;
    float co = c[(long)b * 512 + u];
    float ho = (float)h[(long)b * 512 + u];
    float cn = act[512 + u] * co + act[u] * act[1024 + u];
    float th = 2.0f / (1.0f + __expf(-2.0f * cn)) - 1.0f;
    float hn = act[1536 + u] * th;
    h[(long)b * 512 + u] = (f16)(m ? hn : ho);
    c[(long)b * 512 + u] = m ? cn : co;
  }
}

// ---------------------------------------------------------------------------
// Head: out[b,:] = softmax(h1[b,:] @ Wd + bd)
// ---------------------------------------------------------------------------
__global__ __launch_bounds__(64) void head_kernel(
    const f16* __restrict__ h, const float* __restrict__ Wd,
    const float* __restrict__ bd, float* __restrict__ out) {
  __shared__ float hs[512];
  __shared__ float lg[16];
  int b = blockIdx.x, tid = threadIdx.x;
#pragma unroll
  for (int i = 0; i < 8; ++i) hs[tid + 64 * i] = (float)h[(long)b * 512 + tid + 64 * i];
  __syncthreads();
  if (tid < 14) {
    float s = bd[tid];
    for (int k = 0; k < 512; ++k) s += hs[k] * Wd[k * 14 + tid];
    lg[tid] = s;
  }
  __syncthreads();
  if (tid < 14) {
    float mx = lg[0];
#pragma unroll
    for (int i = 1; i < 14; ++i) mx = fmaxf(mx, lg[i]);
    float e = __expf(lg[tid] - mx);
    float den = 0.0f;
#pragma unroll
    for (int i = 0; i < 14; ++i) den += __expf(lg[i] - mx);
    out[(long)b * 14 + tid] = e / den;
  }
}

// ---------------------------------------------------------------------------
extern "C" void kernel_launch(void* const* d_in, const int* in_sizes, int n_in,
                              void* d_out, int out_size, void* d_ws, size_t ws_size,
                              hipStream_t stream) {
  const float* x   = (const float*)d_in[0];
  const int* mask  = (const int*)d_in[1];
  const float* W0  = (const float*)d_in[2];
  const float* U0w = (const float*)d_in[3];
  const float* b0  = (const float*)d_in[4];
  const float* g0  = (const float*)d_in[5];
  const float* be0 = (const float*)d_in[6];
  const float* W1  = (const float*)d_in[7];
  const float* U1w = (const float*)d_in[8];
  const float* b1  = (const float*)d_in[9];
  const float* g1  = (const float*)d_in[10];
  const float* be1 = (const float*)d_in[11];
  const float* Wd  = (const float*)d_in[12];
  const float* bd  = (const float*)d_in[13];
  float* out = (float*)d_out;

  char* p = (char*)d_ws;
  // layout (all unconditional usage stays < 23.1 MB; zB needs ws >= 30 MiB)
  f16*   h0  = (f16*)(p + 0);                       // 1 MB
  f16*   h1  = (f16*)(p + ((size_t)1 << 20));       // 1 MB
  float* c0  = (float*)(p + ((size_t)2 << 20));     // 2 MB
  float* c1  = (float*)(p + ((size_t)4 << 20));     // 2 MB
  float* zA  = (float*)(p + ((size_t)6 << 20));     // 8 MB  [6,14)
  f16*   W0t = (f16*)(p + ((size_t)14 << 20));                       // 2048*320*2
  f16*   U0t = (f16*)(p + ((size_t)14 << 20) + 1310720);             // 2048*512*2
  f16*   W1t = (f16*)(p + ((size_t)14 << 20) + 1310720 + 2097152);
  f16*   U1t = (f16*)(p + ((size_t)14 << 20) + 1310720 + 2 * 2097152);
  float* zB  = (float*)(p + ((size_t)22 << 20));    // 8 MB [22,30)  (pipelined)
  f16*   xh  = (f16*)(p + ((size_t)22 << 20));      // 0.65 MB       (fallback)

  const bool pipe = ws_size >= ((size_t)30 << 20);

  // zero states (ws is re-poisoned before every call)
  hipMemsetAsync(p, 0, (size_t)6 << 20, stream);

  // weight prep
  transpose_f16<<<dim3(64, 10), 256, 0, stream>>>(W0,  W0t, 300, 2048, 320);
  transpose_f16<<<dim3(64, 16), 256, 0, stream>>>(U0w, U0t, 512, 2048, 512);
  transpose_f16<<<dim3(64, 16), 256, 0, stream>>>(W1,  W1t, 512, 2048, 512);
  transpose_f16<<<dim3(64, 16), 256, 0, stream>>>(U1w, U1t, 512, 2048, 512);

  if (pipe) {
    // pipelined: iteration t computes z0(t) and z1(t-1) together.
    for (int t = 0; t <= 100; ++t) {
      int do0 = (t < 100) ? 1 : 0;
      int do1 = (t >= 1) ? 1 : 0;
      gemm_step<<<dim3(16, 32), 256, 0, stream>>>(
          x + (long)t * 300, h0, h1, W0t, U0t, W1t, U1t, zA, zB, do0, do1);
      ln_gates2<<<2048, 256, 0, stream>>>(
          zA, zB, g0, be0, b0, g1, be1, b1, mask, t, h0, c0, h1, c1, do0, do1);
    }
  } else {
    // fallback: 4-launch-per-step structure (per-step x conversion)
    for (int t = 0; t < 100; ++t) {
      convert_x<<<(1024 * 320 + 255) / 256, 256, 0, stream>>>(x + (long)t * 300, 30000, xh, 1024);
      gemm_f16<<<dim3(16, 16), 256, 0, stream>>>(
          xh, 320, 320, W0t, h0, 512, 512, U0t, zA);
      ln_gates<<<1024, 256, 0, stream>>>(zA, g0, be0, b0, mask, t, h0, c0);
      gemm_f16<<<dim3(16, 16), 256, 0, stream>>>(
          h0, 512, 512, W1t, h1, 512, 512, U1t, zA);
      ln_gates<<<1024, 256, 0, stream>>>(zA, g1, be1, b1, mask, t, h1, c1);
    }
  }

  head_kernel<<<1024, 64, 0, stream>>>(h1, Wd, bd, out);
}